// Round 3
// baseline (313.268 us; speedup 1.0000x reference)
//
#include <hip/hip_runtime.h>
#include <math.h>
#include <stdint.h>

#define LEVELS 80

typedef float f32x4 __attribute__((ext_vector_type(4)));

// Bits of 1/(2*pi) = 0.28BE60DB 9391054A 7F09D5F4 7D4D3770 36D8A566 4F10E410 ...
// Word j holds fractional bits [32j+1 .. 32j+32].
__device__ const uint32_t INV2PI_BITS[9] = {
    0x28BE60DBu, 0x9391054Au, 0x7F09D5F4u, 0x7D4D3770u, 0x36D8A566u,
    0x4F10E410u, 0x7F9458EAu, 0xF7AEF158u, 0x6DC91B8Eu
};

__device__ __forceinline__ uint32_t inv2pi_word(int q) {
    return (q < 0 || q > 8) ? 0u : INV2PI_BITS[q];
}

// Precomputed tables in workspace. Only 64 table bits per exponent are kept:
// the reduced angle uses only hi32(m*T), so words 0..1 of frac(2^E/(2pi))
// suffice (dropped terms perturb the angle by < 2^-31 turns ~ 3e-9 rad).
struct PeTables {
    float2 scale2[LEVELS / 2];  // 320 B
    uint2  t[48];               // 384 B  (x=t0, y=t1)
};

// One-block setup kernel: runs once per launch (~2 us) instead of per block.
__global__ void pe_setup(PeTables* __restrict__ g) {
    __shared__ float s_scale[LEVELS];
    int t = threadIdx.x;
    if (t < LEVELS) {
        // 1.25^t in double-double (exact), rounded to f32 — matches numpy's
        // correctly-rounded f32 pow bit-for-bit; then f32 multiply by f32(pi).
        double hi = 1.0, lo = 0.0;
        for (int j = 0; j < t; ++j) {
            double p = hi * 1.25;
            double e = fma(hi, 1.25, -p);
            lo = fma(lo, 1.25, e);
            double s2 = p + lo;
            lo = lo - (s2 - p);
            hi = s2;
        }
        s_scale[t] = (float)hi * 3.14159274101257324f;
    }
    __syncthreads();
    if (t < LEVELS / 2) {
        g->scale2[t] = make_float2(s_scale[2 * t], s_scale[2 * t + 1]);
    }
    if (t < 48) {
        // frac(2^E/(2pi)) top 64 bits for E = t-22.
        int E = t - 22;
        uint32_t w[2];
        #pragma unroll
        for (int i = 0; i < 2; ++i) {
            int bpos = 32 * i + E;
            int q = bpos >> 5;
            int r = bpos & 31;
            uint64_t win = ((uint64_t)inv2pi_word(q) << 32) | (uint64_t)inv2pi_word(q + 1);
            w[i] = (uint32_t)(win >> (32 - r));
        }
        g->t[t] = make_uint2(w[0], w[1]);
    }
}

// Exact-argument sincos for v >= 0 (f32). frac(v/2pi) high word:
//   fh = lo32(m*t0) + hi32(m*t1)   (2^-32 turn units)
// This equals the old 96-bit path's (f >> 32) to within 1 ulp: the quadrant q
// and residual rhi only ever consumed f's high word, and u32 wraparound of
// (fh + 2^29) >> 30 is exactly mod-4-correct for the quadrant.
__device__ __forceinline__ void sincos_fast(float v, const uint2* __restrict__ s_t,
                                            float& s_out, float& c_out) {
    uint32_t bits = __float_as_uint(v);
    int idx = (int)(bits >> 23) - 128;          // v = m*2^E, idx = E+22 (v > 0)
    idx = idx < 0 ? 0 : (idx > 47 ? 47 : idx);  // v==0 clamped, fixed by final select
    uint32_t m = (bits & 0x7FFFFFu) | 0x800000u;
    uint2 tt = s_t[idx];
    uint32_t fh = m * tt.x + __umulhi(m, tt.y); // frac(v/2pi) in 2^-32 turns
    uint32_t q = (fh + 0x20000000u) >> 30;      // nearest quadrant (mod 4 via wrap)
    int32_t rhi = (int32_t)(fh - (q << 30));    // |rhi| <= 2^29
    float th = (float)rhi * 1.46291807926715968e-9f; // * 2pi/2^32 -> [-pi/4, pi/4]
    float z = th * th;
    float s = th * fmaf(z, fmaf(z, fmaf(z, -1.98412698e-4f, 8.33333333e-3f),
                                 -1.66666667e-1f), 1.0f);
    float c = fmaf(z, fmaf(z, fmaf(z, fmaf(z, 2.48015873e-5f, -1.38888889e-3f),
                                   4.16666667e-2f), -0.5f), 1.0f);
    float ss = (q & 1u) ? c : s;
    float cc = (q & 1u) ? s : c;
    ss = (q & 2u) ? -ss : ss;
    cc = ((q + 1u) & 2u) ? -cc : cc;
    s_out = (bits == 0u) ? 0.0f : ss;
    c_out = (bits == 0u) ? 1.0f : cc;
}

// Main kernel: grid-stride with stride % 40 == 0 so (p, i2) advance without a
// fresh div, and the scale pair is loaded from LDS exactly once per thread.
__global__ __launch_bounds__(256) void pe_main(f32x4* __restrict__ out,
                                               const PeTables* __restrict__ g,
                                               int total) {
    __shared__ float2 s_scale2[LEVELS / 2];
    __shared__ uint2 s_t[48];
    int t = threadIdx.x;
    if (t < LEVELS / 2) s_scale2[t] = g->scale2[t];
    if (t < 48) s_t[t] = g->t[t];
    __syncthreads();

    int stride = (int)(gridDim.x * blockDim.x);   // launch ensures stride % 40 == 0
    uint32_t dp = (uint32_t)stride / 40u;
    int idx = (int)(blockIdx.x * blockDim.x) + t;
    uint32_t u = (uint32_t)idx;
    uint32_t p = u / 40u;                         // position
    uint32_t i2 = u - p * 40u;                    // level pair, invariant across iters
    float2 sc = s_scale2[i2];

    for (; idx < total; idx += stride, p += dp) {
        float pf = (float)p;                      // exact, p < 2^24
        float v0 = pf * sc.x;                     // same f32 rounding as reference
        float v1 = pf * sc.y;
        float s0, c0, s1, c1;
        sincos_fast(v0, s_t, s0, c0);
        sincos_fast(v1, s_t, s1, c1);
        f32x4 r = {s0, c0, s1, c1};
        __builtin_nontemporal_store(r, &out[idx]); // pure-streaming 320 MB write
    }
}

// Fallback (ws too small): original self-contained kernel, verified previously.
__global__ __launch_bounds__(256) void pe_kernel_standalone(float* __restrict__ out, int n_pos) {
    __shared__ float s_scale[LEVELS];
    __shared__ uint32_t s_t0[48], s_t1[48], s_t2[48];
    int t = threadIdx.x;
    if (t < LEVELS) {
        double hi = 1.0, lo = 0.0;
        for (int j = 0; j < t; ++j) {
            double p = hi * 1.25;
            double e = fma(hi, 1.25, -p);
            lo = fma(lo, 1.25, e);
            double s2 = p + lo;
            lo = lo - (s2 - p);
            hi = s2;
        }
        s_scale[t] = (float)hi * 3.14159274101257324f;
    }
    if (t < 48) {
        int E = t - 22;
        uint32_t w[3];
        #pragma unroll
        for (int i = 0; i < 3; ++i) {
            int bpos = 32 * i + E;
            int q = bpos >> 5;
            int r = bpos & 31;
            uint64_t win = ((uint64_t)inv2pi_word(q) << 32) | (uint64_t)inv2pi_word(q + 1);
            w[i] = (uint32_t)(win >> (32 - r));
        }
        s_t0[t] = w[0]; s_t1[t] = w[1]; s_t2[t] = w[2];
    }
    __syncthreads();

    const int total = n_pos * (LEVELS / 2);
    int idx = blockIdx.x * blockDim.x + t;
    if (idx >= total) return;

    uint32_t u = (uint32_t)idx;
    uint32_t p = u / 40u;
    uint32_t i2 = u - p * 40u;
    float pf = (float)p;
    float v0 = pf * s_scale[2 * i2];
    float v1 = pf * s_scale[2 * i2 + 1];

    uint32_t b0 = __float_as_uint(v0);
    uint32_t b1 = __float_as_uint(v1);
    float s0, c0, s1, c1;
    {
        int idx0 = (int)(b0 >> 23) - 128; idx0 = idx0 < 0 ? 0 : (idx0 > 47 ? 47 : idx0);
        uint32_t m = (b0 & 0x7FFFFFu) | 0x800000u;
        uint64_t f = ((uint64_t)(m * s_t0[idx0]) << 32)
                   + (uint64_t)m * (uint64_t)s_t1[idx0]
                   + (((uint64_t)m * (uint64_t)s_t2[idx0]) >> 32);
        uint32_t q = (uint32_t)((f + 0x2000000000000000ULL) >> 62);
        int32_t rhi = (int32_t)((uint32_t)(f >> 32) - (q << 30));
        float th = (float)rhi * 1.46291807926715968e-9f;
        float z = th * th;
        float s = th * fmaf(z, fmaf(z, fmaf(z, -1.98412698e-4f, 8.33333333e-3f), -1.66666667e-1f), 1.0f);
        float c = fmaf(z, fmaf(z, fmaf(z, fmaf(z, 2.48015873e-5f, -1.38888889e-3f), 4.16666667e-2f), -0.5f), 1.0f);
        float ss = (q & 1u) ? c : s; float cc = (q & 1u) ? s : c;
        ss = (q & 2u) ? -ss : ss; cc = ((q + 1u) & 2u) ? -cc : cc;
        s0 = (b0 == 0u) ? 0.0f : ss; c0 = (b0 == 0u) ? 1.0f : cc;
    }
    {
        int idx1 = (int)(b1 >> 23) - 128; idx1 = idx1 < 0 ? 0 : (idx1 > 47 ? 47 : idx1);
        uint32_t m = (b1 & 0x7FFFFFu) | 0x800000u;
        uint64_t f = ((uint64_t)(m * s_t0[idx1]) << 32)
                   + (uint64_t)m * (uint64_t)s_t1[idx1]
                   + (((uint64_t)m * (uint64_t)s_t2[idx1]) >> 32);
        uint32_t q = (uint32_t)((f + 0x2000000000000000ULL) >> 62);
        int32_t rhi = (int32_t)((uint32_t)(f >> 32) - (q << 30));
        float th = (float)rhi * 1.46291807926715968e-9f;
        float z = th * th;
        float s = th * fmaf(z, fmaf(z, fmaf(z, -1.98412698e-4f, 8.33333333e-3f), -1.66666667e-1f), 1.0f);
        float c = fmaf(z, fmaf(z, fmaf(z, fmaf(z, 2.48015873e-5f, -1.38888889e-3f), 4.16666667e-2f), -0.5f), 1.0f);
        float ss = (q & 1u) ? c : s; float cc = (q & 1u) ? s : c;
        ss = (q & 2u) ? -ss : ss; cc = ((q + 1u) & 2u) ? -cc : cc;
        s1 = (b1 == 0u) ? 0.0f : ss; c1 = (b1 == 0u) ? 1.0f : cc;
    }

    float4 r;
    r.x = s0; r.y = c0; r.z = s1; r.w = c1;
    reinterpret_cast<float4*>(out)[idx] = r;
}

extern "C" void kernel_launch(void* const* d_in, const int* in_sizes, int n_in,
                              void* d_out, int out_size, void* d_ws, size_t ws_size,
                              hipStream_t stream) {
    (void)d_in; (void)n_in; (void)out_size;
    int n_pos = in_sizes[0];                  // 500000; pos values unused by reference
    int total = n_pos * (LEVELS / 2);
    int threads = 256;

    if (d_ws != nullptr && ws_size >= sizeof(PeTables)) {
        PeTables* g = (PeTables*)d_ws;
        pe_setup<<<1, 128, 0, stream>>>(g);
        // ~10 items/thread; blocks rounded up to a multiple of 5 so that
        // stride = blocks*256 is divisible by 40 (p advances by stride/40).
        int items = 10;
        int blocks = (total + threads * items - 1) / (threads * items);
        blocks = ((blocks + 4) / 5) * 5;
        pe_main<<<blocks, threads, 0, stream>>>((f32x4*)d_out, g, total);
    } else {
        int blocks = (total + threads - 1) / threads;
        pe_kernel_standalone<<<blocks, threads, 0, stream>>>((float*)d_out, n_pos);
    }
}

// Round 4
// 310.412 us; speedup vs baseline: 1.0092x; 1.0092x over previous
//
#include <hip/hip_runtime.h>
#include <math.h>
#include <stdint.h>

#define LEVELS 80

typedef float f32x4 __attribute__((ext_vector_type(4)));

// Bits of 1/(2*pi) = 0.28BE60DB 9391054A 7F09D5F4 7D4D3770 36D8A566 4F10E410 ...
// Word j holds fractional bits [32j+1 .. 32j+32].
__device__ const uint32_t INV2PI_BITS[9] = {
    0x28BE60DBu, 0x9391054Au, 0x7F09D5F4u, 0x7D4D3770u, 0x36D8A566u,
    0x4F10E410u, 0x7F9458EAu, 0xF7AEF158u, 0x6DC91B8Eu
};

__device__ __forceinline__ uint32_t inv2pi_word(int q) {
    return (q < 0 || q > 8) ? 0u : INV2PI_BITS[q];
}

// Precomputed tables in workspace. Only 64 table bits per exponent are kept:
// the reduced angle uses only hi32(m*T), so words 0..1 of frac(2^E/(2pi))
// suffice (dropped terms perturb the angle by < 2^-31 turns ~ 3e-9 rad).
struct PeTables {
    float2 scale2[LEVELS / 2];  // 320 B
    uint2  t[48];               // 384 B  (x=t0, y=t1)
};

// One-block setup kernel: runs once per launch (~2 us) instead of per block.
__global__ void pe_setup(PeTables* __restrict__ g) {
    __shared__ float s_scale[LEVELS];
    int t = threadIdx.x;
    if (t < LEVELS) {
        // 1.25^t in double-double (exact), rounded to f32 — matches numpy's
        // correctly-rounded f32 pow bit-for-bit; then f32 multiply by f32(pi).
        double hi = 1.0, lo = 0.0;
        for (int j = 0; j < t; ++j) {
            double p = hi * 1.25;
            double e = fma(hi, 1.25, -p);
            lo = fma(lo, 1.25, e);
            double s2 = p + lo;
            lo = lo - (s2 - p);
            hi = s2;
        }
        s_scale[t] = (float)hi * 3.14159274101257324f;
    }
    __syncthreads();
    if (t < LEVELS / 2) {
        g->scale2[t] = make_float2(s_scale[2 * t], s_scale[2 * t + 1]);
    }
    if (t < 48) {
        // frac(2^E/(2pi)) top 64 bits for E = t-22.
        int E = t - 22;
        uint32_t w[2];
        #pragma unroll
        for (int i = 0; i < 2; ++i) {
            int bpos = 32 * i + E;
            int q = bpos >> 5;
            int r = bpos & 31;
            uint64_t win = ((uint64_t)inv2pi_word(q) << 32) | (uint64_t)inv2pi_word(q + 1);
            w[i] = (uint32_t)(win >> (32 - r));
        }
        g->t[t] = make_uint2(w[0], w[1]);
    }
}

// Exact-argument sincos for v >= 0 (f32). frac(v/2pi) high word:
//   fh = lo32(m*t0) + hi32(m*t1)   (2^-32 turn units)
// Equals the 96-bit path's (f >> 32) to within 1 ulp; u32 wraparound of
// (fh + 2^29) >> 30 is exactly mod-4-correct for the quadrant.
__device__ __forceinline__ void sincos_fast(float v, const uint2* __restrict__ s_t,
                                            float& s_out, float& c_out) {
    uint32_t bits = __float_as_uint(v);
    int idx = (int)(bits >> 23) - 128;          // v = m*2^E, idx = E+22 (v > 0)
    idx = idx < 0 ? 0 : (idx > 47 ? 47 : idx);  // v==0 clamped, fixed by final select
    uint32_t m = (bits & 0x7FFFFFu) | 0x800000u;
    uint2 tt = s_t[idx];
    uint32_t fh = m * tt.x + __umulhi(m, tt.y); // frac(v/2pi) in 2^-32 turns
    uint32_t q = (fh + 0x20000000u) >> 30;      // nearest quadrant (mod 4 via wrap)
    int32_t rhi = (int32_t)(fh - (q << 30));    // |rhi| <= 2^29
    float th = (float)rhi * 1.46291807926715968e-9f; // * 2pi/2^32 -> [-pi/4, pi/4]
    float z = th * th;
    float s = th * fmaf(z, fmaf(z, fmaf(z, -1.98412698e-4f, 8.33333333e-3f),
                                 -1.66666667e-1f), 1.0f);
    float c = fmaf(z, fmaf(z, fmaf(z, fmaf(z, 2.48015873e-5f, -1.38888889e-3f),
                                   4.16666667e-2f), -0.5f), 1.0f);
    float ss = (q & 1u) ? c : s;
    float cc = (q & 1u) ? s : c;
    ss = (q & 2u) ? -ss : ss;
    cc = ((q + 1u) & 2u) ? -cc : cc;
    s_out = (bits == 0u) ? 0.0f : ss;
    c_out = (bits == 0u) ? 1.0f : cc;
}

// Main kernel: grid-stride with stride % 40 == 0 so (p, i2) advance without a
// fresh div. A/B vs R3: PLAIN stores (nontemporal removed — suspect nt's
// no-allocate path is the 4.3 vs 6.3 TB/s gap) + 2x unroll for two
// independent store streams per thread.
__global__ __launch_bounds__(256) void pe_main(f32x4* __restrict__ out,
                                               const PeTables* __restrict__ g,
                                               int total) {
    __shared__ float2 s_scale2[LEVELS / 2];
    __shared__ uint2 s_t[48];
    int t = threadIdx.x;
    if (t < LEVELS / 2) s_scale2[t] = g->scale2[t];
    if (t < 48) s_t[t] = g->t[t];
    __syncthreads();

    int stride = (int)(gridDim.x * blockDim.x);   // launch ensures stride % 40 == 0
    uint32_t dp = (uint32_t)stride / 40u;
    int idx = (int)(blockIdx.x * blockDim.x) + t;
    uint32_t u = (uint32_t)idx;
    uint32_t p = u / 40u;                         // position
    uint32_t i2 = u - p * 40u;                    // level pair, invariant across iters
    float2 sc = s_scale2[i2];

    #pragma unroll 2
    for (; idx < total; idx += stride, p += dp) {
        float pf = (float)p;                      // exact, p < 2^24
        float v0 = pf * sc.x;                     // same f32 rounding as reference
        float v1 = pf * sc.y;
        float s0, c0, s1, c1;
        sincos_fast(v0, s_t, s0, c0);
        sincos_fast(v1, s_t, s1, c1);
        f32x4 r = {s0, c0, s1, c1};
        out[idx] = r;                             // plain streaming store (via L2)
    }
}

// Fallback (ws too small): original self-contained kernel, verified previously.
__global__ __launch_bounds__(256) void pe_kernel_standalone(float* __restrict__ out, int n_pos) {
    __shared__ float s_scale[LEVELS];
    __shared__ uint32_t s_t0[48], s_t1[48], s_t2[48];
    int t = threadIdx.x;
    if (t < LEVELS) {
        double hi = 1.0, lo = 0.0;
        for (int j = 0; j < t; ++j) {
            double p = hi * 1.25;
            double e = fma(hi, 1.25, -p);
            lo = fma(lo, 1.25, e);
            double s2 = p + lo;
            lo = lo - (s2 - p);
            hi = s2;
        }
        s_scale[t] = (float)hi * 3.14159274101257324f;
    }
    if (t < 48) {
        int E = t - 22;
        uint32_t w[3];
        #pragma unroll
        for (int i = 0; i < 3; ++i) {
            int bpos = 32 * i + E;
            int q = bpos >> 5;
            int r = bpos & 31;
            uint64_t win = ((uint64_t)inv2pi_word(q) << 32) | (uint64_t)inv2pi_word(q + 1);
            w[i] = (uint32_t)(win >> (32 - r));
        }
        s_t0[t] = w[0]; s_t1[t] = w[1]; s_t2[t] = w[2];
    }
    __syncthreads();

    const int total = n_pos * (LEVELS / 2);
    int idx = blockIdx.x * blockDim.x + t;
    if (idx >= total) return;

    uint32_t u = (uint32_t)idx;
    uint32_t p = u / 40u;
    uint32_t i2 = u - p * 40u;
    float pf = (float)p;
    float v0 = pf * s_scale[2 * i2];
    float v1 = pf * s_scale[2 * i2 + 1];

    uint32_t b0 = __float_as_uint(v0);
    uint32_t b1 = __float_as_uint(v1);
    float s0, c0, s1, c1;
    {
        int idx0 = (int)(b0 >> 23) - 128; idx0 = idx0 < 0 ? 0 : (idx0 > 47 ? 47 : idx0);
        uint32_t m = (b0 & 0x7FFFFFu) | 0x800000u;
        uint64_t f = ((uint64_t)(m * s_t0[idx0]) << 32)
                   + (uint64_t)m * (uint64_t)s_t1[idx0]
                   + (((uint64_t)m * (uint64_t)s_t2[idx0]) >> 32);
        uint32_t q = (uint32_t)((f + 0x2000000000000000ULL) >> 62);
        int32_t rhi = (int32_t)((uint32_t)(f >> 32) - (q << 30));
        float th = (float)rhi * 1.46291807926715968e-9f;
        float z = th * th;
        float s = th * fmaf(z, fmaf(z, fmaf(z, -1.98412698e-4f, 8.33333333e-3f), -1.66666667e-1f), 1.0f);
        float c = fmaf(z, fmaf(z, fmaf(z, fmaf(z, 2.48015873e-5f, -1.38888889e-3f), 4.16666667e-2f), -0.5f), 1.0f);
        float ss = (q & 1u) ? c : s; float cc = (q & 1u) ? s : c;
        ss = (q & 2u) ? -ss : ss; cc = ((q + 1u) & 2u) ? -cc : cc;
        s0 = (b0 == 0u) ? 0.0f : ss; c0 = (b0 == 0u) ? 1.0f : cc;
    }
    {
        int idx1 = (int)(b1 >> 23) - 128; idx1 = idx1 < 0 ? 0 : (idx1 > 47 ? 47 : idx1);
        uint32_t m = (b1 & 0x7FFFFFu) | 0x800000u;
        uint64_t f = ((uint64_t)(m * s_t0[idx1]) << 32)
                   + (uint64_t)m * (uint64_t)s_t1[idx1]
                   + (((uint64_t)m * (uint64_t)s_t2[idx1]) >> 32);
        uint32_t q = (uint32_t)((f + 0x2000000000000000ULL) >> 62);
        int32_t rhi = (int32_t)((uint32_t)(f >> 32) - (q << 30));
        float th = (float)rhi * 1.46291807926715968e-9f;
        float z = th * th;
        float s = th * fmaf(z, fmaf(z, fmaf(z, -1.98412698e-4f, 8.33333333e-3f), -1.66666667e-1f), 1.0f);
        float c = fmaf(z, fmaf(z, fmaf(z, fmaf(z, 2.48015873e-5f, -1.38888889e-3f), 4.16666667e-2f), -0.5f), 1.0f);
        float ss = (q & 1u) ? c : s; float cc = (q & 1u) ? s : c;
        ss = (q & 2u) ? -ss : ss; cc = ((q + 1u) & 2u) ? -cc : cc;
        s1 = (b1 == 0u) ? 0.0f : ss; c1 = (b1 == 0u) ? 1.0f : cc;
    }

    float4 r;
    r.x = s0; r.y = c0; r.z = s1; r.w = c1;
    reinterpret_cast<float4*>(out)[idx] = r;
}

extern "C" void kernel_launch(void* const* d_in, const int* in_sizes, int n_in,
                              void* d_out, int out_size, void* d_ws, size_t ws_size,
                              hipStream_t stream) {
    (void)d_in; (void)n_in; (void)out_size;
    int n_pos = in_sizes[0];                  // 500000; pos values unused by reference
    int total = n_pos * (LEVELS / 2);
    int threads = 256;

    if (d_ws != nullptr && ws_size >= sizeof(PeTables)) {
        PeTables* g = (PeTables*)d_ws;
        pe_setup<<<1, 128, 0, stream>>>(g);
        // ~10 items/thread; blocks rounded up to a multiple of 5 so that
        // stride = blocks*256 is divisible by 40 (p advances by stride/40).
        int items = 10;
        int blocks = (total + threads * items - 1) / (threads * items);
        blocks = ((blocks + 4) / 5) * 5;
        pe_main<<<blocks, threads, 0, stream>>>((f32x4*)d_out, g, total);
    } else {
        int blocks = (total + threads - 1) / threads;
        pe_kernel_standalone<<<blocks, threads, 0, stream>>>((float*)d_out, n_pos);
    }
}